// Round 10
// baseline (273.639 us; speedup 1.0000x reference)
//
#include <hip/hip_runtime.h>
#include <math.h>
#include <stdint.h>

#define NQ 10
#define DEPTH 6

typedef _Float16 f16x8 __attribute__((ext_vector_type(8)));
typedef float f32x4 __attribute__((ext_vector_type(4)));

typedef __attribute__((address_space(3))) unsigned int lds_u32;
typedef const __attribute__((address_space(1))) unsigned int glb_u32;

__device__ __forceinline__ void async_load16(const unsigned short* g, unsigned short* l) {
    __builtin_amdgcn_global_load_lds((glb_u32*)g, (lds_u32*)l, 16, 0, 0);
}

// ---------------------------------------------------------------------------
// Gate precompute: Rot = RZ(omega) RY(theta) RZ(phi)
// ---------------------------------------------------------------------------
__device__ __forceinline__ void compute_gate(const float* __restrict__ weights,
                                             int idx, float* __restrict__ g) {
    float phi   = weights[idx * 3 + 0];
    float theta = weights[idx * 3 + 1];
    float omega = weights[idx * 3 + 2];
    float c = cosf(0.5f * theta), s = sinf(0.5f * theta);
    float ap = -0.5f * (phi + omega);
    float am = -0.5f * (phi - omega);
    float epr = cosf(ap), epi = sinf(ap);
    float emr = cosf(am), emi = sinf(am);
    g[0] =  epr * c;  g[1] =  epi * c;
    g[2] = -emr * s;  g[3] =  emi * s;
    g[4] =  emr * s;  g[5] =  emi * s;
    g[6] =  epr * c;  g[7] = -epi * c;
}

__global__ void prep_gates_kernel(const float* __restrict__ weights,
                                  float* __restrict__ gmat) {
    int idx = blockIdx.x * blockDim.x + threadIdx.x;
    if (idx >= DEPTH * NQ) return;
    compute_gate(weights, idx, gmat + idx * 8);
}

// ---------------------------------------------------------------------------
// Circuit core (verified): one wave holds 1024 amps; shuffles batched.
// amp index: bits 0..3 slot, 4..9 lane.
// ---------------------------------------------------------------------------
__device__ __forceinline__ void apply_1q_local(
    float (&ar)[16], float (&ai)[16], int q,
    float u00r, float u00i, float u01r, float u01i,
    float u10r, float u10i, float u11r, float u11i) {
#pragma unroll
    for (int j = 0; j < 16; ++j) {
        if ((j >> q) & 1) continue;
        int j1 = j | (1 << q);
        float a0r = ar[j],  a0i = ai[j];
        float a1r = ar[j1], a1i = ai[j1];
        ar[j]  = u00r*a0r - u00i*a0i + u01r*a1r - u01i*a1i;
        ai[j]  = u00r*a0i + u00i*a0r + u01r*a1i + u01i*a1r;
        ar[j1] = u10r*a0r - u10i*a0i + u11r*a1r - u11i*a1i;
        ai[j1] = u10r*a0i + u10i*a0r + u11r*a1i + u11i*a1r;
    }
}

__device__ __forceinline__ void apply_1q_lane(
    float (&ar)[16], float (&ai)[16], int q, int lane,
    float u00r, float u00i, float u01r, float u01i,
    float u10r, float u10i, float u11r, float u11i) {
    int  m  = 1 << (q - 4);
    bool hi = (lane >> (q - 4)) & 1;
    float car = hi ? u11r : u00r, cai = hi ? u11i : u00i;
    float cbr = hi ? u10r : u01r, cbi = hi ? u10i : u01i;
    float pr[16], pi[16];
#pragma unroll
    for (int j = 0; j < 16; ++j) pr[j] = __shfl_xor(ar[j], m, 64);
#pragma unroll
    for (int j = 0; j < 16; ++j) pi[j] = __shfl_xor(ai[j], m, 64);
#pragma unroll
    for (int j = 0; j < 16; ++j) {
        float mr = ar[j], mi = ai[j];
        ar[j] = car*mr - cai*mi + cbr*pr[j] - cbi*pi[j];
        ai[j] = car*mi + cai*mr + cbr*pi[j] + cbi*pr[j];
    }
}

__device__ __forceinline__ void cnot_gate(
    float (&ar)[16], float (&ai)[16], int c, int t, int lane) {
    if (c < 4 && t < 4) {
#pragma unroll
        for (int j = 0; j < 16; ++j) {
            if (((j >> c) & 1) && !((j >> t) & 1)) {
                int j1 = j | (1 << t);
                float tr = ar[j]; ar[j] = ar[j1]; ar[j1] = tr;
                float ti = ai[j]; ai[j] = ai[j1]; ai[j1] = ti;
            }
        }
    } else if (c < 4) {
        int m = 1 << (t - 4);
        float pr[16], pi[16];
#pragma unroll
        for (int j = 0; j < 16; ++j)
            if ((j >> c) & 1) pr[j] = __shfl_xor(ar[j], m, 64);
#pragma unroll
        for (int j = 0; j < 16; ++j)
            if ((j >> c) & 1) pi[j] = __shfl_xor(ai[j], m, 64);
#pragma unroll
        for (int j = 0; j < 16; ++j)
            if ((j >> c) & 1) { ar[j] = pr[j]; ai[j] = pi[j]; }
    } else if (t < 4) {
        bool cb = (lane >> (c - 4)) & 1;
#pragma unroll
        for (int j = 0; j < 16; ++j) {
            if (!((j >> t) & 1)) {
                int j1 = j | (1 << t);
                float lr = ar[j], li = ai[j], hr = ar[j1], hi2 = ai[j1];
                ar[j]  = cb ? hr : lr;  ai[j]  = cb ? hi2 : li;
                ar[j1] = cb ? lr : hr;  ai[j1] = cb ? li : hi2;
            }
        }
    } else {
        int  m  = 1 << (t - 4);
        bool cb = (lane >> (c - 4)) & 1;
        float pr[16], pi[16];
#pragma unroll
        for (int j = 0; j < 16; ++j) pr[j] = __shfl_xor(ar[j], m, 64);
#pragma unroll
        for (int j = 0; j < 16; ++j) pi[j] = __shfl_xor(ai[j], m, 64);
#pragma unroll
        for (int j = 0; j < 16; ++j) {
            ar[j] = cb ? pr[j] : ar[j];
            ai[j] = cb ? pi[j] : ai[j];
        }
    }
}

template <int R>
__device__ __forceinline__ void cnot_ring(float (&ar)[16], float (&ai)[16], int lane) {
#pragma unroll
    for (int i = 0; i < NQ; ++i) cnot_gate(ar, ai, i, (i + R) % NQ, lane);
}

template <int R>
__device__ __forceinline__ void cnot_ring_rev(float (&ar)[16], float (&ai)[16], int lane) {
#pragma unroll
    for (int i = NQ - 1; i >= 0; --i) cnot_gate(ar, ai, i, (i + R) % NQ, lane);
}

// forward circuit (fallback vqc_kernel)
__device__ __forceinline__ void run_circuit(float (&ar)[16], float (&ai)[16],
                                            const float* __restrict__ gmat, int lane) {
    for (int l = 0; l < DEPTH; ++l) {
        const float* gl = gmat + l * (NQ * 8);
#pragma unroll
        for (int i = 0; i < NQ; ++i) {
            const float* g = gl + i * 8;
            float u00r = g[0], u00i = g[1], u01r = g[2], u01i = g[3];
            float u10r = g[4], u10i = g[5], u11r = g[6], u11i = g[7];
            if (i < 4)
                apply_1q_local(ar, ai, i, u00r,u00i,u01r,u01i,u10r,u10i,u11r,u11i);
            else
                apply_1q_lane(ar, ai, i, lane, u00r,u00i,u01r,u01i,u10r,u10i,u11r,u11i);
        }
        switch (l) {
            case 0: cnot_ring<1>(ar, ai, lane); break;
            case 1: cnot_ring<2>(ar, ai, lane); break;
            case 2: cnot_ring<3>(ar, ai, lane); break;
            case 3: cnot_ring<4>(ar, ai, lane); break;
            case 4: cnot_ring<5>(ar, ai, lane); break;
            default: cnot_ring<6>(ar, ai, lane); break;
        }
    }
}

// transposed circuit (verified round 8): wave computes row g of U.
__device__ __forceinline__ void run_circuit_T(float (&ar)[16], float (&ai)[16],
                                              const float* __restrict__ gmat, int lane) {
    for (int l = DEPTH - 1; l >= 0; --l) {
        switch (l) {
            case 0: cnot_ring_rev<1>(ar, ai, lane); break;
            case 1: cnot_ring_rev<2>(ar, ai, lane); break;
            case 2: cnot_ring_rev<3>(ar, ai, lane); break;
            case 3: cnot_ring_rev<4>(ar, ai, lane); break;
            case 4: cnot_ring_rev<5>(ar, ai, lane); break;
            default: cnot_ring_rev<6>(ar, ai, lane); break;
        }
        const float* gl = gmat + l * (NQ * 8);
#pragma unroll
        for (int i = 0; i < NQ; ++i) {
            const float* g = gl + i * 8;
            float u00r = g[0], u00i = g[1];
            float u01r = g[4], u01i = g[5];   // transposed: u01 = orig u10
            float u10r = g[2], u10i = g[3];   // transposed: u10 = orig u01
            float u11r = g[6], u11i = g[7];
            if (i < 4)
                apply_1q_local(ar, ai, i, u00r,u00i,u01r,u01i,u10r,u10i,u11r,u11i);
            else
                apply_1q_lane(ar, ai, i, lane, u00r,u00i,u01r,u01i,u10r,u10i,u11r,u11i);
        }
    }
}

__device__ __forceinline__ float wave_sum(float v) {
#pragma unroll
    for (int m = 1; m < 64; m <<= 1) v += __shfl_xor(v, m, 64);
    return v;
}

// ---------------------------------------------------------------------------
// proj body: float4 loads (44 load-issues/lane instead of 176).
// ---------------------------------------------------------------------------
__device__ __forceinline__ void proj_v_body(
    const float* __restrict__ x, const float* __restrict__ Wproj,
    _Float16* __restrict__ V, int b, int lane) {
    const float4* xb4 = (const float4*)(x + (size_t)b * 1024);
    const float4* W4  = (const float4*)Wproj;        // [q][256]
    float acc[NQ];
#pragma unroll
    for (int q = 0; q < NQ; ++q) acc[q] = 0.f;
#pragma unroll
    for (int k4 = 0; k4 < 4; ++k4) {
        float4 xv = xb4[k4 * 64 + lane];
#pragma unroll
        for (int q = 0; q < NQ; ++q) {
            float4 wv = W4[q * 256 + k4 * 64 + lane];
            acc[q] = fmaf(xv.x, wv.x, acc[q]);
            acc[q] = fmaf(xv.y, wv.y, acc[q]);
            acc[q] = fmaf(xv.z, wv.z, acc[q]);
            acc[q] = fmaf(xv.w, wv.w, acc[q]);
        }
    }
#pragma unroll
    for (int q = 0; q < NQ; ++q) acc[q] = wave_sum(acc[q]);

    float cq[NQ], sq[NQ];
#pragma unroll
    for (int q = 0; q < NQ; ++q) {
        float ang = tanhf(acc[q]) * 1.57079632679489662f;
        cq[q] = cosf(0.5f * ang);
        sq[q] = sinf(0.5f * ang);
    }
    float laneprod = 1.f;
#pragma unroll
    for (int q = 4; q < NQ; ++q)
        laneprod *= ((lane >> (q - 4)) & 1) ? sq[q] : cq[q];

    unsigned int buf[8];
#pragma unroll
    for (int jj = 0; jj < 8; ++jj) {
        unsigned short h2[2];
#pragma unroll
        for (int c = 0; c < 2; ++c) {
            int j = jj * 2 + c;
            float p = laneprod;
#pragma unroll
            for (int q = 0; q < 4; ++q) p *= ((j >> q) & 1) ? sq[q] : cq[q];
            h2[c] = __builtin_bit_cast(unsigned short, (_Float16)p);
        }
        buf[jj] = (unsigned int)h2[0] | ((unsigned int)h2[1] << 16);
    }
    uint4* dst = (uint4*)(V + (size_t)b * 1024 + 16 * lane);
    uint4 v0; v0.x = buf[0]; v0.y = buf[1]; v0.z = buf[2]; v0.w = buf[3];
    uint4 v1; v1.x = buf[4]; v1.y = buf[5]; v1.z = buf[6]; v1.w = buf[7];
    dst[0] = v0; dst[1] = v1;
}

// ---------------------------------------------------------------------------
// Kernel A: blocks [0,256): gates(LDS) + transposed basis sim -> Bt rows.
//           blocks [256, 256+B/4): projection -> V.
//           last block: zero the per-m-tile completion counters.
// ---------------------------------------------------------------------------
__global__ __launch_bounds__(256) void basis_proj_kernel(
    const float* __restrict__ weights, _Float16* __restrict__ Bt,
    const float* __restrict__ x, const float* __restrict__ Wproj,
    _Float16* __restrict__ V, int* __restrict__ cnt, int B) {
    __shared__ float gmat_s[DEPTH * NQ * 8];
    int tid  = threadIdx.x;
    int lane = tid & 63;
    int w    = tid >> 6;
    int nproj = B / 4;

    if (blockIdx.x < 256) {
        if (tid < DEPTH * NQ) compute_gate(weights, tid, gmat_s + tid * 8);
        __syncthreads();

        int g = blockIdx.x * 4 + w;          // basis index = output row pair
        float ar[16], ai[16];
#pragma unroll
        for (int jj = 0; jj < 16; ++jj) {
            ar[jj] = (lane == (g >> 4) && jj == (g & 15)) ? 1.f : 0.f;
            ai[jj] = 0.f;
        }
        run_circuit_T(ar, ai, gmat_s, lane);

        unsigned int bufr[8], bufi[8];
#pragma unroll
        for (int jj = 0; jj < 8; ++jj) {
            unsigned short r0 = __builtin_bit_cast(unsigned short, (_Float16)ar[2*jj]);
            unsigned short r1 = __builtin_bit_cast(unsigned short, (_Float16)ar[2*jj+1]);
            unsigned short i0 = __builtin_bit_cast(unsigned short, (_Float16)ai[2*jj]);
            unsigned short i1 = __builtin_bit_cast(unsigned short, (_Float16)ai[2*jj+1]);
            bufr[jj] = (unsigned int)r0 | ((unsigned int)r1 << 16);
            bufi[jj] = (unsigned int)i0 | ((unsigned int)i1 << 16);
        }
        uint4* dre = (uint4*)((unsigned short*)Bt + (size_t)(2*g)     * 1024 + 16 * lane);
        uint4* dim = (uint4*)((unsigned short*)Bt + (size_t)(2*g + 1) * 1024 + 16 * lane);
        uint4 v;
        v.x = bufr[0]; v.y = bufr[1]; v.z = bufr[2]; v.w = bufr[3]; dre[0] = v;
        v.x = bufr[4]; v.y = bufr[5]; v.z = bufr[6]; v.w = bufr[7]; dre[1] = v;
        v.x = bufi[0]; v.y = bufi[1]; v.z = bufi[2]; v.w = bufi[3]; dim[0] = v;
        v.x = bufi[4]; v.y = bufi[5]; v.z = bufi[6]; v.w = bufi[7]; dim[1] = v;
    } else if (blockIdx.x < 256 + nproj) {
        int b = (blockIdx.x - 256) * 4 + w;
        if (b < B) proj_v_body(x, Wproj, V, b, lane);
    } else {
        for (int i = tid; i < B / 128; i += 256) cnt[i] = 0;
    }
}

// ---------------------------------------------------------------------------
// Kernel B: fused GEMM + |psi|^2 + partial-Z + last-block combine + head.
// Zpart: (B,16,8) floats. One counter atomic per block; the 16th block per
// m-tile combines (thread-per-row, contiguous 512B reads) and writes out.
// ---------------------------------------------------------------------------
__global__ __launch_bounds__(256) void gemm_fused_kernel(
    const unsigned short* __restrict__ A,    // V (B,1024)
    const unsigned short* __restrict__ Bt,   // (2048,1024)
    float* __restrict__ Zpart,               // (B,16,8)
    int* __restrict__ cnt,                   // (B/128,) zeroed by kernel A
    const float* __restrict__ Wout, const float* __restrict__ bout,
    float* __restrict__ out) {               // (B,10)
    __shared__ unsigned short As[128 * 64];
    __shared__ unsigned short Bs[128 * 64];
    __shared__ float WoutS[NQ * NQ];
    __shared__ float boutS[NQ];
    __shared__ int lastFlag;
    int tid  = threadIdx.x;
    int lane = tid & 63;
    int w    = tid >> 6;
    int m0   = blockIdx.x * 128;
    int nb   = blockIdx.y;
    int n0   = nb * 128;
    int mh   = (w >> 1) * 64, nh = (w & 1) * 64;
    int quad = lane >> 4;
    int lrow = lane & 15;
    int srow  = (lane >> 3);
    int schnk = (lane & 7) ^ srow;

    if (tid < NQ * NQ) WoutS[tid] = Wout[tid];
    if (tid < NQ) boutS[tid] = bout[tid];

    f32x4 acc[4][4];
#pragma unroll
    for (int mi = 0; mi < 4; ++mi)
#pragma unroll
        for (int ni = 0; ni < 4; ++ni)
            acc[mi][ni] = (f32x4){0.f, 0.f, 0.f, 0.f};

    for (int kt = 0; kt < 16; ++kt) {
        if (kt) __syncthreads();
#pragma unroll
        for (int r = 0; r < 4; ++r) {
            int s   = w * 4 + r;
            int row = s * 8 + srow;
            async_load16(A  + (size_t)(m0 + row) * 1024 + kt * 64 + schnk * 8,
                         As + s * 512);
            async_load16(Bt + (size_t)(n0 + row) * 1024 + kt * 64 + schnk * 8,
                         Bs + s * 512);
        }
        asm volatile("s_waitcnt vmcnt(0)" ::: "memory");
        __syncthreads();
#pragma unroll
        for (int kk = 0; kk < 2; ++kk) {
            f16x8 af[4], bf[4];
#pragma unroll
            for (int i = 0; i < 4; ++i) {
                int cxa = (kk * 4 + quad) ^ (lrow & 7);
                af[i] = *(const f16x8*)(As + (mh + i * 16 + lrow) * 64 + cxa * 8);
                bf[i] = *(const f16x8*)(Bs + (nh + i * 16 + lrow) * 64 + cxa * 8);
            }
#pragma unroll
            for (int mi = 0; mi < 4; ++mi)
#pragma unroll
                for (int ni = 0; ni < 4; ++ni)
                    acc[mi][ni] = __builtin_amdgcn_mfma_f32_16x16x32_f16(
                        af[mi], bf[ni], acc[mi][ni], 0, 0, 0);
        }
    }

    // ---- epilogue: square + signed reduce (verified; stride-9 LDS) ----
    __syncthreads();
    float* Zs = (float*)As;                  // [2][128][9] = 9216 B
#pragma unroll
    for (int mi = 0; mi < 4; ++mi) {
#pragma unroll
        for (int r = 0; r < 4; ++r) {
            float p0 = acc[mi][0][r] * acc[mi][0][r];
            float p1 = acc[mi][1][r] * acc[mi][1][r];
            float p2 = acc[mi][2][r] * acc[mi][2][r];
            float p3 = acc[mi][3][r] * acc[mi][3][r];
            float t0 = (p0 + p1) + (p2 + p3);
            float t3 = (p0 - p1) + (p2 - p3);
            float t4 = (p0 + p1) - (p2 + p3);
            t0 += __shfl_xor(t0, 1, 64);
            t3 += __shfl_xor(t3, 1, 64);
            t4 += __shfl_xor(t4, 1, 64);
            float u2 = __shfl_xor(t0, 2, 64);
            float ap = t0 + u2;
            float am = (lane & 2) ? u2 - t0 : t0 - u2;
            t3 += __shfl_xor(t3, 2, 64);
            t4 += __shfl_xor(t4, 2, 64);
            float u4  = __shfl_xor(ap, 4, 64);
            float bpp = ap + u4;
            float bpm = (lane & 4) ? u4 - ap : ap - u4;
            float bmp = am + __shfl_xor(am, 4, 64);
            t3 += __shfl_xor(t3, 4, 64);
            t4 += __shfl_xor(t4, 4, 64);
            float u8 = __shfl_xor(bpp, 8, 64);
            float T  = bpp + u8;
            float Z2 = (lane & 8) ? u8 - bpp : bpp - u8;
            float Z1 = bpm + __shfl_xor(bpm, 8, 64);
            float Z0 = bmp + __shfl_xor(bmp, 8, 64);
            t3 += __shfl_xor(t3, 8, 64);
            t4 += __shfl_xor(t4, 8, 64);
            if (lrow == 0) {
                int row = mh + mi * 16 + quad * 4 + r;
                float* z = Zs + ((size_t)(w & 1) * 128 + row) * 9;
                z[0] = T;  z[1] = Z0; z[2] = Z1; z[3] = Z2;
                z[4] = t3; z[5] = t4;
            }
        }
    }
    __syncthreads();
    {
        int row  = tid >> 1, part = tid & 1;
        const float* za = Zs + (size_t)row * 9;
        const float* zb = Zs + (size_t)(128 + row) * 9;
        float o[4];
        if (part == 0) {
            o[0] = za[0] + zb[0];            // T
            o[1] = za[1] + zb[1];            // Z0
            o[2] = za[2] + zb[2];            // Z1
            o[3] = za[3] + zb[3];            // Z2
        } else {
            o[0] = za[4] + zb[4];            // Z3
            o[1] = za[5] + zb[5];            // Z4
            o[2] = za[0] - zb[0];            // Z5
            o[3] = 0.f;
        }
        float4 v = {o[0], o[1], o[2], o[3]};
        *(float4*)(Zpart + ((size_t)(m0 + row) * 16 + nb) * 8 + part * 4) = v;
    }

    // ---- completion counter; 16th block combines + writes out ----
    __threadfence();                          // release this block's Zpart
    __syncthreads();
    if (tid == 0) {
        int old = atomicAdd(&cnt[blockIdx.x], 1);
        lastFlag = (old == 15);
    }
    __syncthreads();
    if (!lastFlag) return;
    __threadfence();                          // acquire other blocks' Zpart
    if (tid < 128) {
        int b = m0 + tid;
        const float4* zp = (const float4*)(Zpart + (size_t)b * 16 * 8);
        float Zq[NQ];
#pragma unroll
        for (int q = 0; q < NQ; ++q) Zq[q] = 0.f;
#pragma unroll
        for (int t = 0; t < 16; ++t) {
            float4 a = zp[t * 2];
            float4 c = zp[t * 2 + 1];
            float T = a.x;
            Zq[0] += a.y; Zq[1] += a.z; Zq[2] += a.w;
            Zq[3] += c.x; Zq[4] += c.y; Zq[5] += c.z;
            Zq[6] += (t & 1) ? -T : T;
            Zq[7] += (t & 2) ? -T : T;
            Zq[8] += (t & 4) ? -T : T;
            Zq[9] += (t & 8) ? -T : T;
        }
        float* op = out + (size_t)b * NQ;
#pragma unroll
        for (int c = 0; c < NQ; ++c) {
            float o = boutS[c];
#pragma unroll
            for (int q = 0; q < NQ; ++q) o = fmaf(Zq[q], WoutS[c * NQ + q], o);
            op[c] = o;
        }
    }
}

// ---------------------------------------------------------------------------
// Fallback: round-1 monolithic kernel (verified).
// ---------------------------------------------------------------------------
__global__ __launch_bounds__(256) void vqc_kernel(
    const float* __restrict__ x, const float* __restrict__ Wproj,
    const float* __restrict__ gmat, const float* __restrict__ Wout,
    const float* __restrict__ bout, float* __restrict__ out, int B) {
    int lane = threadIdx.x & 63;
    int wid  = threadIdx.x >> 6;
    int b    = blockIdx.x * 4 + wid;
    if (b >= B) return;

    const float* xb = x + (size_t)b * 1024;
    float acc[NQ];
#pragma unroll
    for (int q = 0; q < NQ; ++q) acc[q] = 0.f;
#pragma unroll
    for (int k = 0; k < 16; ++k) {
        float xv = xb[k * 64 + lane];
#pragma unroll
        for (int q = 0; q < NQ; ++q)
            acc[q] = fmaf(xv, Wproj[q * 1024 + k * 64 + lane], acc[q]);
    }
#pragma unroll
    for (int q = 0; q < NQ; ++q) acc[q] = wave_sum(acc[q]);

    float cq[NQ], sq[NQ];
#pragma unroll
    for (int q = 0; q < NQ; ++q) {
        float ang = tanhf(acc[q]) * 1.57079632679489662f;
        cq[q] = cosf(0.5f * ang);
        sq[q] = sinf(0.5f * ang);
    }
    float laneprod = 1.f;
#pragma unroll
    for (int q = 4; q < NQ; ++q)
        laneprod *= ((lane >> (q - 4)) & 1) ? sq[q] : cq[q];
    float ar[16], ai[16];
#pragma unroll
    for (int j = 0; j < 16; ++j) {
        float p = laneprod;
#pragma unroll
        for (int q = 0; q < 4; ++q) p *= ((j >> q) & 1) ? sq[q] : cq[q];
        ar[j] = p; ai[j] = 0.f;
    }
    run_circuit(ar, ai, gmat, lane);

    float T = 0.f, S[4] = {0.f, 0.f, 0.f, 0.f};
#pragma unroll
    for (int j = 0; j < 16; ++j) {
        float p = ar[j] * ar[j] + ai[j] * ai[j];
        T += p;
#pragma unroll
        for (int q = 0; q < 4; ++q) S[q] += ((j >> q) & 1) ? -p : p;
    }
    float Zq[NQ];
#pragma unroll
    for (int q = 0; q < 4; ++q) Zq[q] = S[q];
#pragma unroll
    for (int q = 4; q < NQ; ++q) Zq[q] = ((lane >> (q - 4)) & 1) ? -T : T;
#pragma unroll
    for (int q = 0; q < NQ; ++q) Zq[q] = wave_sum(Zq[q]);
    if (lane < NQ) {
        float o = bout[lane];
#pragma unroll
        for (int q = 0; q < NQ; ++q) o = fmaf(Zq[q], Wout[lane * NQ + q], o);
        out[(size_t)b * NQ + lane] = o;
    }
}

extern "C" void kernel_launch(void* const* d_in, const int* in_sizes, int n_in,
                              void* d_out, int out_size, void* d_ws, size_t ws_size,
                              hipStream_t stream) {
    const float* x       = (const float*)d_in[0];
    const float* Wproj   = (const float*)d_in[1];
    const float* weights = (const float*)d_in[2];
    const float* Wout    = (const float*)d_in[3];
    const float* bout    = (const float*)d_in[4];
    float* out = (float*)d_out;
    int B = in_sizes[0] / 1024;

    char* ws = (char*)d_ws;
    size_t off_Bt = 4096;
    size_t off_V  = off_Bt + (size_t)2048 * 1024 * 2;
    size_t off_Z  = off_V  + (size_t)B * 1024 * 2;
    size_t off_C  = off_Z  + (size_t)B * 16 * 8 * 4;
    size_t need   = off_C  + 4096;

    if (ws_size >= need && (B % 128) == 0) {
        _Float16* Bt = (_Float16*)(ws + off_Bt);
        _Float16* V  = (_Float16*)(ws + off_V);
        float*  Zprt = (float*)(ws + off_Z);
        int*    cnt  = (int*)(ws + off_C);

        basis_proj_kernel<<<256 + B / 4 + 1, 256, 0, stream>>>(
            weights, Bt, x, Wproj, V, cnt, B);
        gemm_fused_kernel<<<dim3(B / 128, 16), 256, 0, stream>>>(
            (const unsigned short*)V, (const unsigned short*)Bt,
            Zprt, cnt, Wout, bout, out);
    } else {
        float* gmat = (float*)ws;
        prep_gates_kernel<<<1, 64, 0, stream>>>(weights, gmat);
        vqc_kernel<<<(B + 3) / 4, 256, 0, stream>>>(x, Wproj, gmat, Wout, bout, out, B);
    }
}

// Round 11
// 159.825 us; speedup vs baseline: 1.7121x; 1.7121x over previous
//
#include <hip/hip_runtime.h>
#include <math.h>
#include <stdint.h>

#define NQ 10
#define DEPTH 6

typedef _Float16 f16x8 __attribute__((ext_vector_type(8)));
typedef float f32x4 __attribute__((ext_vector_type(4)));

typedef __attribute__((address_space(3))) unsigned int lds_u32;
typedef const __attribute__((address_space(1))) unsigned int glb_u32;

__device__ __forceinline__ void async_load16(const unsigned short* g, unsigned short* l) {
    __builtin_amdgcn_global_load_lds((glb_u32*)g, (lds_u32*)l, 16, 0, 0);
}

// ---------------------------------------------------------------------------
// Gate precompute: Rot = RZ(omega) RY(theta) RZ(phi)
// ---------------------------------------------------------------------------
__device__ __forceinline__ void compute_gate(const float* __restrict__ weights,
                                             int idx, float* __restrict__ g) {
    float phi   = weights[idx * 3 + 0];
    float theta = weights[idx * 3 + 1];
    float omega = weights[idx * 3 + 2];
    float c = cosf(0.5f * theta), s = sinf(0.5f * theta);
    float ap = -0.5f * (phi + omega);
    float am = -0.5f * (phi - omega);
    float epr = cosf(ap), epi = sinf(ap);
    float emr = cosf(am), emi = sinf(am);
    g[0] =  epr * c;  g[1] =  epi * c;
    g[2] = -emr * s;  g[3] =  emi * s;
    g[4] =  emr * s;  g[5] =  emi * s;
    g[6] =  epr * c;  g[7] = -epi * c;
}

__global__ void prep_gates_kernel(const float* __restrict__ weights,
                                  float* __restrict__ gmat) {
    int idx = blockIdx.x * blockDim.x + threadIdx.x;
    if (idx >= DEPTH * NQ) return;
    compute_gate(weights, idx, gmat + idx * 8);
}

// ---------------------------------------------------------------------------
// Circuit core (verified): one wave holds 1024 amps; shuffles batched.
// amp index: bits 0..3 slot, 4..9 lane.
// ---------------------------------------------------------------------------
__device__ __forceinline__ void apply_1q_local(
    float (&ar)[16], float (&ai)[16], int q,
    float u00r, float u00i, float u01r, float u01i,
    float u10r, float u10i, float u11r, float u11i) {
#pragma unroll
    for (int j = 0; j < 16; ++j) {
        if ((j >> q) & 1) continue;
        int j1 = j | (1 << q);
        float a0r = ar[j],  a0i = ai[j];
        float a1r = ar[j1], a1i = ai[j1];
        ar[j]  = u00r*a0r - u00i*a0i + u01r*a1r - u01i*a1i;
        ai[j]  = u00r*a0i + u00i*a0r + u01r*a1i + u01i*a1r;
        ar[j1] = u10r*a0r - u10i*a0i + u11r*a1r - u11i*a1i;
        ai[j1] = u10r*a0i + u10i*a0r + u11r*a1i + u11i*a1r;
    }
}

__device__ __forceinline__ void apply_1q_lane(
    float (&ar)[16], float (&ai)[16], int q, int lane,
    float u00r, float u00i, float u01r, float u01i,
    float u10r, float u10i, float u11r, float u11i) {
    int  m  = 1 << (q - 4);
    bool hi = (lane >> (q - 4)) & 1;
    float car = hi ? u11r : u00r, cai = hi ? u11i : u00i;
    float cbr = hi ? u10r : u01r, cbi = hi ? u10i : u01i;
    float pr[16], pi[16];
#pragma unroll
    for (int j = 0; j < 16; ++j) pr[j] = __shfl_xor(ar[j], m, 64);
#pragma unroll
    for (int j = 0; j < 16; ++j) pi[j] = __shfl_xor(ai[j], m, 64);
#pragma unroll
    for (int j = 0; j < 16; ++j) {
        float mr = ar[j], mi = ai[j];
        ar[j] = car*mr - cai*mi + cbr*pr[j] - cbi*pi[j];
        ai[j] = car*mi + cai*mr + cbr*pi[j] + cbi*pr[j];
    }
}

__device__ __forceinline__ void cnot_gate(
    float (&ar)[16], float (&ai)[16], int c, int t, int lane) {
    if (c < 4 && t < 4) {
#pragma unroll
        for (int j = 0; j < 16; ++j) {
            if (((j >> c) & 1) && !((j >> t) & 1)) {
                int j1 = j | (1 << t);
                float tr = ar[j]; ar[j] = ar[j1]; ar[j1] = tr;
                float ti = ai[j]; ai[j] = ai[j1]; ai[j1] = ti;
            }
        }
    } else if (c < 4) {
        int m = 1 << (t - 4);
        float pr[16], pi[16];
#pragma unroll
        for (int j = 0; j < 16; ++j)
            if ((j >> c) & 1) pr[j] = __shfl_xor(ar[j], m, 64);
#pragma unroll
        for (int j = 0; j < 16; ++j)
            if ((j >> c) & 1) pi[j] = __shfl_xor(ai[j], m, 64);
#pragma unroll
        for (int j = 0; j < 16; ++j)
            if ((j >> c) & 1) { ar[j] = pr[j]; ai[j] = pi[j]; }
    } else if (t < 4) {
        bool cb = (lane >> (c - 4)) & 1;
#pragma unroll
        for (int j = 0; j < 16; ++j) {
            if (!((j >> t) & 1)) {
                int j1 = j | (1 << t);
                float lr = ar[j], li = ai[j], hr = ar[j1], hi2 = ai[j1];
                ar[j]  = cb ? hr : lr;  ai[j]  = cb ? hi2 : li;
                ar[j1] = cb ? lr : hr;  ai[j1] = cb ? li : hi2;
            }
        }
    } else {
        int  m  = 1 << (t - 4);
        bool cb = (lane >> (c - 4)) & 1;
        float pr[16], pi[16];
#pragma unroll
        for (int j = 0; j < 16; ++j) pr[j] = __shfl_xor(ar[j], m, 64);
#pragma unroll
        for (int j = 0; j < 16; ++j) pi[j] = __shfl_xor(ai[j], m, 64);
#pragma unroll
        for (int j = 0; j < 16; ++j) {
            ar[j] = cb ? pr[j] : ar[j];
            ai[j] = cb ? pi[j] : ai[j];
        }
    }
}

template <int R>
__device__ __forceinline__ void cnot_ring(float (&ar)[16], float (&ai)[16], int lane) {
#pragma unroll
    for (int i = 0; i < NQ; ++i) cnot_gate(ar, ai, i, (i + R) % NQ, lane);
}

template <int R>
__device__ __forceinline__ void cnot_ring_rev(float (&ar)[16], float (&ai)[16], int lane) {
#pragma unroll
    for (int i = NQ - 1; i >= 0; --i) cnot_gate(ar, ai, i, (i + R) % NQ, lane);
}

// forward circuit (fallback vqc_kernel)
__device__ __forceinline__ void run_circuit(float (&ar)[16], float (&ai)[16],
                                            const float* __restrict__ gmat, int lane) {
    for (int l = 0; l < DEPTH; ++l) {
        const float* gl = gmat + l * (NQ * 8);
#pragma unroll
        for (int i = 0; i < NQ; ++i) {
            const float* g = gl + i * 8;
            float u00r = g[0], u00i = g[1], u01r = g[2], u01i = g[3];
            float u10r = g[4], u10i = g[5], u11r = g[6], u11i = g[7];
            if (i < 4)
                apply_1q_local(ar, ai, i, u00r,u00i,u01r,u01i,u10r,u10i,u11r,u11i);
            else
                apply_1q_lane(ar, ai, i, lane, u00r,u00i,u01r,u01i,u10r,u10i,u11r,u11i);
        }
        switch (l) {
            case 0: cnot_ring<1>(ar, ai, lane); break;
            case 1: cnot_ring<2>(ar, ai, lane); break;
            case 2: cnot_ring<3>(ar, ai, lane); break;
            case 3: cnot_ring<4>(ar, ai, lane); break;
            case 4: cnot_ring<5>(ar, ai, lane); break;
            default: cnot_ring<6>(ar, ai, lane); break;
        }
    }
}

// transposed circuit (verified round 8): wave computes row g of U.
__device__ __forceinline__ void run_circuit_T(float (&ar)[16], float (&ai)[16],
                                              const float* __restrict__ gmat, int lane) {
    for (int l = DEPTH - 1; l >= 0; --l) {
        switch (l) {
            case 0: cnot_ring_rev<1>(ar, ai, lane); break;
            case 1: cnot_ring_rev<2>(ar, ai, lane); break;
            case 2: cnot_ring_rev<3>(ar, ai, lane); break;
            case 3: cnot_ring_rev<4>(ar, ai, lane); break;
            case 4: cnot_ring_rev<5>(ar, ai, lane); break;
            default: cnot_ring_rev<6>(ar, ai, lane); break;
        }
        const float* gl = gmat + l * (NQ * 8);
#pragma unroll
        for (int i = 0; i < NQ; ++i) {
            const float* g = gl + i * 8;
            float u00r = g[0], u00i = g[1];
            float u01r = g[4], u01i = g[5];   // transposed: u01 = orig u10
            float u10r = g[2], u10i = g[3];   // transposed: u10 = orig u01
            float u11r = g[6], u11i = g[7];
            if (i < 4)
                apply_1q_local(ar, ai, i, u00r,u00i,u01r,u01i,u10r,u10i,u11r,u11i);
            else
                apply_1q_lane(ar, ai, i, lane, u00r,u00i,u01r,u01i,u10r,u10i,u11r,u11i);
        }
    }
}

__device__ __forceinline__ float wave_sum(float v) {
#pragma unroll
    for (int m = 1; m < 64; m <<= 1) v += __shfl_xor(v, m, 64);
    return v;
}

// ---------------------------------------------------------------------------
// proj body: float4 loads (verified round 10).
// ---------------------------------------------------------------------------
__device__ __forceinline__ void proj_v_body(
    const float* __restrict__ x, const float* __restrict__ Wproj,
    _Float16* __restrict__ V, int b, int lane) {
    const float4* xb4 = (const float4*)(x + (size_t)b * 1024);
    const float4* W4  = (const float4*)Wproj;        // [q][256]
    float acc[NQ];
#pragma unroll
    for (int q = 0; q < NQ; ++q) acc[q] = 0.f;
#pragma unroll
    for (int k4 = 0; k4 < 4; ++k4) {
        float4 xv = xb4[k4 * 64 + lane];
#pragma unroll
        for (int q = 0; q < NQ; ++q) {
            float4 wv = W4[q * 256 + k4 * 64 + lane];
            acc[q] = fmaf(xv.x, wv.x, acc[q]);
            acc[q] = fmaf(xv.y, wv.y, acc[q]);
            acc[q] = fmaf(xv.z, wv.z, acc[q]);
            acc[q] = fmaf(xv.w, wv.w, acc[q]);
        }
    }
#pragma unroll
    for (int q = 0; q < NQ; ++q) acc[q] = wave_sum(acc[q]);

    float cq[NQ], sq[NQ];
#pragma unroll
    for (int q = 0; q < NQ; ++q) {
        float ang = tanhf(acc[q]) * 1.57079632679489662f;
        cq[q] = cosf(0.5f * ang);
        sq[q] = sinf(0.5f * ang);
    }
    float laneprod = 1.f;
#pragma unroll
    for (int q = 4; q < NQ; ++q)
        laneprod *= ((lane >> (q - 4)) & 1) ? sq[q] : cq[q];

    unsigned int buf[8];
#pragma unroll
    for (int jj = 0; jj < 8; ++jj) {
        unsigned short h2[2];
#pragma unroll
        for (int c = 0; c < 2; ++c) {
            int j = jj * 2 + c;
            float p = laneprod;
#pragma unroll
            for (int q = 0; q < 4; ++q) p *= ((j >> q) & 1) ? sq[q] : cq[q];
            h2[c] = __builtin_bit_cast(unsigned short, (_Float16)p);
        }
        buf[jj] = (unsigned int)h2[0] | ((unsigned int)h2[1] << 16);
    }
    uint4* dst = (uint4*)(V + (size_t)b * 1024 + 16 * lane);
    uint4 v0; v0.x = buf[0]; v0.y = buf[1]; v0.z = buf[2]; v0.w = buf[3];
    uint4 v1; v1.x = buf[4]; v1.y = buf[5]; v1.z = buf[6]; v1.w = buf[7];
    dst[0] = v0; dst[1] = v1;
}

// ---------------------------------------------------------------------------
// Kernel A: blocks [0,256): gates(LDS) + transposed basis sim -> Bt rows
//           (coalesced 2KB row writes, verified round 8).
//           blocks [256,...): projection -> V.
// ---------------------------------------------------------------------------
__global__ __launch_bounds__(256) void basis_proj_kernel(
    const float* __restrict__ weights, _Float16* __restrict__ Bt,
    const float* __restrict__ x, const float* __restrict__ Wproj,
    _Float16* __restrict__ V, int B) {
    __shared__ float gmat_s[DEPTH * NQ * 8];
    int tid  = threadIdx.x;
    int lane = tid & 63;
    int w    = tid >> 6;

    if (blockIdx.x < 256) {
        if (tid < DEPTH * NQ) compute_gate(weights, tid, gmat_s + tid * 8);
        __syncthreads();

        int g = blockIdx.x * 4 + w;          // basis index = output row pair
        float ar[16], ai[16];
#pragma unroll
        for (int jj = 0; jj < 16; ++jj) {
            ar[jj] = (lane == (g >> 4) && jj == (g & 15)) ? 1.f : 0.f;
            ai[jj] = 0.f;
        }
        run_circuit_T(ar, ai, gmat_s, lane);

        unsigned int bufr[8], bufi[8];
#pragma unroll
        for (int jj = 0; jj < 8; ++jj) {
            unsigned short r0 = __builtin_bit_cast(unsigned short, (_Float16)ar[2*jj]);
            unsigned short r1 = __builtin_bit_cast(unsigned short, (_Float16)ar[2*jj+1]);
            unsigned short i0 = __builtin_bit_cast(unsigned short, (_Float16)ai[2*jj]);
            unsigned short i1 = __builtin_bit_cast(unsigned short, (_Float16)ai[2*jj+1]);
            bufr[jj] = (unsigned int)r0 | ((unsigned int)r1 << 16);
            bufi[jj] = (unsigned int)i0 | ((unsigned int)i1 << 16);
        }
        uint4* dre = (uint4*)((unsigned short*)Bt + (size_t)(2*g)     * 1024 + 16 * lane);
        uint4* dim = (uint4*)((unsigned short*)Bt + (size_t)(2*g + 1) * 1024 + 16 * lane);
        uint4 v;
        v.x = bufr[0]; v.y = bufr[1]; v.z = bufr[2]; v.w = bufr[3]; dre[0] = v;
        v.x = bufr[4]; v.y = bufr[5]; v.z = bufr[6]; v.w = bufr[7]; dre[1] = v;
        v.x = bufi[0]; v.y = bufi[1]; v.z = bufi[2]; v.w = bufi[3]; dim[0] = v;
        v.x = bufi[4]; v.y = bufi[5]; v.z = bufi[6]; v.w = bufi[7]; dim[1] = v;
    } else {
        int b = (blockIdx.x - 256) * 4 + w;
        if (b < B) proj_v_body(x, Wproj, V, b, lane);
    }
}

// ---------------------------------------------------------------------------
// Kernel B: fused GEMM + |psi|^2 + partial-Z reduction (verified round 4/5/8;
// stride-9 Zs: zero LDS bank conflicts, verified rounds 9/10).
// ---------------------------------------------------------------------------
__global__ __launch_bounds__(256) void gemm_fused_kernel(
    const unsigned short* __restrict__ A,    // V (B,1024)
    const unsigned short* __restrict__ Bt,   // (2048,1024)
    float* __restrict__ Zpart) {             // (B,16,8)
    __shared__ unsigned short As[128 * 64];
    __shared__ unsigned short Bs[128 * 64];
    int tid  = threadIdx.x;
    int lane = tid & 63;
    int w    = tid >> 6;
    int m0   = blockIdx.x * 128;
    int nb   = blockIdx.y;
    int n0   = nb * 128;
    int mh   = (w >> 1) * 64, nh = (w & 1) * 64;
    int quad = lane >> 4;
    int lrow = lane & 15;
    int srow  = (lane >> 3);
    int schnk = (lane & 7) ^ srow;

    f32x4 acc[4][4];
#pragma unroll
    for (int mi = 0; mi < 4; ++mi)
#pragma unroll
        for (int ni = 0; ni < 4; ++ni)
            acc[mi][ni] = (f32x4){0.f, 0.f, 0.f, 0.f};

    for (int kt = 0; kt < 16; ++kt) {
        if (kt) __syncthreads();
#pragma unroll
        for (int r = 0; r < 4; ++r) {
            int s   = w * 4 + r;
            int row = s * 8 + srow;
            async_load16(A  + (size_t)(m0 + row) * 1024 + kt * 64 + schnk * 8,
                         As + s * 512);
            async_load16(Bt + (size_t)(n0 + row) * 1024 + kt * 64 + schnk * 8,
                         Bs + s * 512);
        }
        asm volatile("s_waitcnt vmcnt(0)" ::: "memory");
        __syncthreads();
#pragma unroll
        for (int kk = 0; kk < 2; ++kk) {
            f16x8 af[4], bf[4];
#pragma unroll
            for (int i = 0; i < 4; ++i) {
                int cxa = (kk * 4 + quad) ^ (lrow & 7);
                af[i] = *(const f16x8*)(As + (mh + i * 16 + lrow) * 64 + cxa * 8);
                bf[i] = *(const f16x8*)(Bs + (nh + i * 16 + lrow) * 64 + cxa * 8);
            }
#pragma unroll
            for (int mi = 0; mi < 4; ++mi)
#pragma unroll
                for (int ni = 0; ni < 4; ++ni)
                    acc[mi][ni] = __builtin_amdgcn_mfma_f32_16x16x32_f16(
                        af[mi], bf[ni], acc[mi][ni], 0, 0, 0);
        }
    }

    // ---- epilogue: square + signed reduce (stride-9 LDS, conflict-free) ----
    __syncthreads();
    float* Zs = (float*)As;                  // [2][128][9] = 9216 B
#pragma unroll
    for (int mi = 0; mi < 4; ++mi) {
#pragma unroll
        for (int r = 0; r < 4; ++r) {
            float p0 = acc[mi][0][r] * acc[mi][0][r];
            float p1 = acc[mi][1][r] * acc[mi][1][r];
            float p2 = acc[mi][2][r] * acc[mi][2][r];
            float p3 = acc[mi][3][r] * acc[mi][3][r];
            float t0 = (p0 + p1) + (p2 + p3);
            float t3 = (p0 - p1) + (p2 - p3);
            float t4 = (p0 + p1) - (p2 + p3);
            t0 += __shfl_xor(t0, 1, 64);
            t3 += __shfl_xor(t3, 1, 64);
            t4 += __shfl_xor(t4, 1, 64);
            float u2 = __shfl_xor(t0, 2, 64);
            float ap = t0 + u2;
            float am = (lane & 2) ? u2 - t0 : t0 - u2;
            t3 += __shfl_xor(t3, 2, 64);
            t4 += __shfl_xor(t4, 2, 64);
            float u4  = __shfl_xor(ap, 4, 64);
            float bpp = ap + u4;
            float bpm = (lane & 4) ? u4 - ap : ap - u4;
            float bmp = am + __shfl_xor(am, 4, 64);
            t3 += __shfl_xor(t3, 4, 64);
            t4 += __shfl_xor(t4, 4, 64);
            float u8 = __shfl_xor(bpp, 8, 64);
            float T  = bpp + u8;
            float Z2 = (lane & 8) ? u8 - bpp : bpp - u8;
            float Z1 = bpm + __shfl_xor(bpm, 8, 64);
            float Z0 = bmp + __shfl_xor(bmp, 8, 64);
            t3 += __shfl_xor(t3, 8, 64);
            t4 += __shfl_xor(t4, 8, 64);
            if (lrow == 0) {
                int row = mh + mi * 16 + quad * 4 + r;
                float* z = Zs + ((size_t)(w & 1) * 128 + row) * 9;
                z[0] = T;  z[1] = Z0; z[2] = Z1; z[3] = Z2;
                z[4] = t3; z[5] = t4;
            }
        }
    }
    __syncthreads();
    {
        int row  = tid >> 1, part = tid & 1;
        const float* za = Zs + (size_t)row * 9;
        const float* zb = Zs + (size_t)(128 + row) * 9;
        float o[4];
        if (part == 0) {
            o[0] = za[0] + zb[0];            // T
            o[1] = za[1] + zb[1];            // Z0
            o[2] = za[2] + zb[2];            // Z1
            o[3] = za[3] + zb[3];            // Z2
        } else {
            o[0] = za[4] + zb[4];            // Z3
            o[1] = za[5] + zb[5];            // Z4
            o[2] = za[0] - zb[0];            // Z5
            o[3] = 0.f;
        }
        float4 v = {o[0], o[1], o[2], o[3]};
        *(float4*)(Zpart + ((size_t)(m0 + row) * 16 + nb) * 8 + part * 4) = v;
    }
}

// ---------------------------------------------------------------------------
// Kernel C: combine 16 n-tile partials -> Z_q -> output head (verified r8).
// ---------------------------------------------------------------------------
__global__ __launch_bounds__(256) void combine_head_kernel(
    const float* __restrict__ Zpart, const float* __restrict__ Wout,
    const float* __restrict__ bout, float* __restrict__ out, int B) {
    int lane = threadIdx.x & 63;
    int wid  = threadIdx.x >> 6;
    int b    = blockIdx.x * 4 + wid;
    if (b >= B) return;

    float z[8];
    if (lane < 16) {
        const float4* p = (const float4*)(Zpart + ((size_t)b * 16 + lane) * 8);
        float4 a = p[0], c = p[1];
        z[0]=a.x; z[1]=a.y; z[2]=a.z; z[3]=a.w; z[4]=c.x; z[5]=c.y; z[6]=c.z; z[7]=c.w;
    } else {
#pragma unroll
        for (int i = 0; i < 8; ++i) z[i] = 0.f;
    }
    float Zq[NQ];
#pragma unroll
    for (int q = 0; q < 6; ++q) {
        float v = z[q + 1];
        v += __shfl_xor(v, 1, 64);
        v += __shfl_xor(v, 2, 64);
        v += __shfl_xor(v, 4, 64);
        v += __shfl_xor(v, 8, 64);
        Zq[q] = v;
    }
    {
        float T = z[0];
        float u1 = __shfl_xor(T, 1, 64);
        float P  = T + u1;
        float M  = (lane & 1) ? u1 - T : T - u1;
        float u2 = __shfl_xor(P, 2, 64);
        float PP = P + u2;
        float PM = (lane & 2) ? u2 - P : P - u2;
        float MP = M + __shfl_xor(M, 2, 64);
        float u4  = __shfl_xor(PP, 4, 64);
        float PPP = PP + u4;
        float PPM = (lane & 4) ? u4 - PP : PP - u4;
        float PMP = PM + __shfl_xor(PM, 4, 64);
        float MPP = MP + __shfl_xor(MP, 4, 64);
        float u8 = __shfl_xor(PPP, 8, 64);
        Zq[9] = (lane & 8) ? u8 - PPP : PPP - u8;
        Zq[8] = PPM + __shfl_xor(PPM, 8, 64);
        Zq[7] = PMP + __shfl_xor(PMP, 8, 64);
        Zq[6] = MPP + __shfl_xor(MPP, 8, 64);
    }
    if (lane < NQ) {
        float o = bout[lane];
#pragma unroll
        for (int q = 0; q < NQ; ++q) o = fmaf(Zq[q], Wout[lane * NQ + q], o);
        out[(size_t)b * NQ + lane] = o;
    }
}

// ---------------------------------------------------------------------------
// Fallback: round-1 monolithic kernel (verified).
// ---------------------------------------------------------------------------
__global__ __launch_bounds__(256) void vqc_kernel(
    const float* __restrict__ x, const float* __restrict__ Wproj,
    const float* __restrict__ gmat, const float* __restrict__ Wout,
    const float* __restrict__ bout, float* __restrict__ out, int B) {
    int lane = threadIdx.x & 63;
    int wid  = threadIdx.x >> 6;
    int b    = blockIdx.x * 4 + wid;
    if (b >= B) return;

    const float* xb = x + (size_t)b * 1024;
    float acc[NQ];
#pragma unroll
    for (int q = 0; q < NQ; ++q) acc[q] = 0.f;
#pragma unroll
    for (int k = 0; k < 16; ++k) {
        float xv = xb[k * 64 + lane];
#pragma unroll
        for (int q = 0; q < NQ; ++q)
            acc[q] = fmaf(xv, Wproj[q * 1024 + k * 64 + lane], acc[q]);
    }
#pragma unroll
    for (int q = 0; q < NQ; ++q) acc[q] = wave_sum(acc[q]);

    float cq[NQ], sq[NQ];
#pragma unroll
    for (int q = 0; q < NQ; ++q) {
        float ang = tanhf(acc[q]) * 1.57079632679489662f;
        cq[q] = cosf(0.5f * ang);
        sq[q] = sinf(0.5f * ang);
    }
    float laneprod = 1.f;
#pragma unroll
    for (int q = 4; q < NQ; ++q)
        laneprod *= ((lane >> (q - 4)) & 1) ? sq[q] : cq[q];
    float ar[16], ai[16];
#pragma unroll
    for (int j = 0; j < 16; ++j) {
        float p = laneprod;
#pragma unroll
        for (int q = 0; q < 4; ++q) p *= ((j >> q) & 1) ? sq[q] : cq[q];
        ar[j] = p; ai[j] = 0.f;
    }
    run_circuit(ar, ai, gmat, lane);

    float T = 0.f, S[4] = {0.f, 0.f, 0.f, 0.f};
#pragma unroll
    for (int j = 0; j < 16; ++j) {
        float p = ar[j] * ar[j] + ai[j] * ai[j];
        T += p;
#pragma unroll
        for (int q = 0; q < 4; ++q) S[q] += ((j >> q) & 1) ? -p : p;
    }
    float Zq[NQ];
#pragma unroll
    for (int q = 0; q < 4; ++q) Zq[q] = S[q];
#pragma unroll
    for (int q = 4; q < NQ; ++q) Zq[q] = ((lane >> (q - 4)) & 1) ? -T : T;
#pragma unroll
    for (int q = 0; q < NQ; ++q) Zq[q] = wave_sum(Zq[q]);
    if (lane < NQ) {
        float o = bout[lane];
#pragma unroll
        for (int q = 0; q < NQ; ++q) o = fmaf(Zq[q], Wout[lane * NQ + q], o);
        out[(size_t)b * NQ + lane] = o;
    }
}

extern "C" void kernel_launch(void* const* d_in, const int* in_sizes, int n_in,
                              void* d_out, int out_size, void* d_ws, size_t ws_size,
                              hipStream_t stream) {
    const float* x       = (const float*)d_in[0];
    const float* Wproj   = (const float*)d_in[1];
    const float* weights = (const float*)d_in[2];
    const float* Wout    = (const float*)d_in[3];
    const float* bout    = (const float*)d_in[4];
    float* out = (float*)d_out;
    int B = in_sizes[0] / 1024;

    char* ws = (char*)d_ws;
    size_t off_Bt = 4096;
    size_t off_V  = off_Bt + (size_t)2048 * 1024 * 2;
    size_t off_Z  = off_V  + (size_t)B * 1024 * 2;
    size_t need   = off_Z  + (size_t)B * 16 * 8 * 4;

    if (ws_size >= need && (B % 128) == 0) {
        _Float16* Bt = (_Float16*)(ws + off_Bt);
        _Float16* V  = (_Float16*)(ws + off_V);
        float*  Zprt = (float*)(ws + off_Z);

        basis_proj_kernel<<<256 + B / 4, 256, 0, stream>>>(weights, Bt, x, Wproj, V, B);
        gemm_fused_kernel<<<dim3(B / 128, 16), 256, 0, stream>>>(
            (const unsigned short*)V, (const unsigned short*)Bt, Zprt);
        combine_head_kernel<<<B / 4, 256, 0, stream>>>(Zprt, Wout, bout, out, B);
    } else {
        float* gmat = (float*)ws;
        prep_gates_kernel<<<1, 64, 0, stream>>>(weights, gmat);
        vqc_kernel<<<(B + 3) / 4, 256, 0, stream>>>(x, Wproj, gmat, Wout, bout, out, B);
    }
}